// Round 4
// baseline (414.820 us; speedup 1.0000x reference)
//
#include <hip/hip_runtime.h>
#include <hip/hip_bf16.h>
#include <stdint.h>

#define H2    512
#define BATCH 32
#define SEQ   4096
#define BM    64
#define BKS   32          // K per tile
#define NKT3  32          // 1024 / 32

typedef __attribute__((ext_vector_type(4))) float f32x4;
typedef __attribute__((ext_vector_type(8))) short bf16x8;

typedef __attribute__((address_space(3))) unsigned int       as3_uint;
typedef const __attribute__((address_space(1))) unsigned int as1_uint;

// RNE fp32 -> bf16
__device__ __forceinline__ unsigned short f2bf(float f) {
    union { float f; unsigned u; } v; v.f = f;
    unsigned r = v.u + 0x7FFF + ((v.u >> 16) & 1);
    return (unsigned short)(r >> 16);
}

__device__ __forceinline__ float fast_tanh(float x) {
    float e = __builtin_amdgcn_exp2f(x * 2.88539008177793f);
    return 1.0f - 2.0f * __builtin_amdgcn_rcpf(e + 1.0f);
}

// ---------------------------------------------------------------------------
// Prep 1: W = [W_h; W_c] -> bf16 FRAGMENT-MAJOR (identical layout to R1/R2):
// chunk c = (kt32*32 + cb)*64 + lane holds 16B:
//   B[col = cb*16 + (lane&15)][k = kt32*32 + (lane>>4)*8 + j], j=0..7
// (kt32 = 32-wide k-tile index 0..31, cb = col-frag 0..31)
// ---------------------------------------------------------------------------
__global__ void kprep_w(const float* __restrict__ Wh, const float* __restrict__ Wc,
                        unsigned short* __restrict__ wt) {
    int c    = blockIdx.x * blockDim.x + threadIdx.x;   // 65536 chunks
    int lane = c & 63;
    int cb   = (c >> 6) & 31;
    int kt   = c >> 11;                                  // 0..31
    int col  = cb * 16 + (lane & 15);
    int k0   = kt * 32 + (lane >> 4) * 8;
    unsigned short tmp[8];
#pragma unroll
    for (int j = 0; j < 8; ++j) {
        int kg = k0 + j;
        float w = (kg < 512) ? Wh[kg * 512 + col] : Wc[(kg - 512) * 512 + col];
        tmp[j] = f2bf(w);
    }
    *reinterpret_cast<uint4*>(wt + (size_t)c * 8) = *reinterpret_cast<const uint4*>(tmp);
}

// ---------------------------------------------------------------------------
// Prep 2: q[b][h] = dec[b]@W_s + b_h + b_s + b_c
// ---------------------------------------------------------------------------
__global__ void kprep_q(const float* __restrict__ dec, const float* __restrict__ Ws,
                        const float* __restrict__ bh, const float* __restrict__ bs,
                        const float* __restrict__ bc, float* __restrict__ q) {
    __shared__ float dsh[512];
    int b = blockIdx.x, t = threadIdx.x;               // 256 threads
    dsh[t]       = dec[b * 512 + t];
    dsh[t + 256] = dec[b * 512 + 256 + t];
    __syncthreads();
    float a0 = 0.f, a1 = 0.f;
#pragma unroll 4
    for (int k = 0; k < 512; ++k) {
        float d = dsh[k];
        a0 = fmaf(d, Ws[k * 512 + t], a0);
        a1 = fmaf(d, Ws[k * 512 + 256 + t], a1);
    }
    q[b * 512 + t]       = a0 + bh[t] + bs[t] + bc[t];
    q[b * 512 + 256 + t] = a1 + bh[256 + t] + bs[256 + t] + bc[256 + t];
}

// ---------------------------------------------------------------------------
// Main fused GEMM v3.
// LDS (dynamic 72KB): Bsm[2][32KB] frag-major | Asm[2][4KB] frag-major.
// B: global_load_lds, wave-private frags, 1 tile ahead (vmcnt(0) at tile
//    start is ~free: loads are one full tile old).
// A: fp32 glb regs (issued tile start) -> cvt bf16 -> ds_write (tile end).
// One barrier per tile; lgkm-only fence; vmem survives the barrier.
// ---------------------------------------------------------------------------
__launch_bounds__(512, 4)
__global__ void kgemm(const float* __restrict__ enc, const float* __restrict__ cov,
                      const unsigned short* __restrict__ wt,
                      const float* __restrict__ q, const float* __restrict__ vvec,
                      float* __restrict__ scores) {
    extern __shared__ char lds[];
    // [0,65536): Bsm two 32KB buffers; [65536,73728): Asm two 4KB buffers
    unsigned short* Bsm = (unsigned short*)lds;
    unsigned short* Asm = (unsigned short*)(lds + 65536);

    int tid  = threadIdx.x;
    int lane = tid & 63, wn = tid >> 6;

    // XCD-aware bijective swizzle (2048 % 8 == 0)
    int cpx  = gridDim.x >> 3;
    int swz  = (blockIdx.x & 7) * cpx + (blockIdx.x >> 3);
    int row0 = swz * BM;

    // ---- A staging addressing (threads 0..255): r = t>>2, k8 = t&3 ----
    int r = tid >> 2, k8 = tid & 3;      // valid when tid < 256
    const float* aeb = enc + (size_t)(row0 + r) * H2 + k8 * 8;
    const float* acb = cov + (size_t)(row0 + r) * H2 + k8 * 8;
    // frag-major A write: byte = (r>>4)*1024 + k8*256 + ((r&15)*16 ^ (k8<<4))
    unsigned awb = (unsigned)((r >> 4) * 1024 + k8 * 256 +
                              (((r & 15) * 16) ^ (k8 << 4)));
    // A frag read (lane): byte = mi*1024 + (l>>4)*256 + ((l&15)*16 ^ ((l>>4)<<4))
    unsigned arb = (unsigned)((lane >> 4) * 256 +
                              (((lane & 15) * 16) ^ ((lane >> 4) << 4)));
    // B frag read: contiguous
    unsigned brb = (unsigned)(wn * 4096 + lane * 16);
    // gll: wave-uniform LDS dest base; per-lane global src
    const unsigned short* gsrc = wt + ((size_t)wn * 4 * 64 + lane) * 8;

    f32x4 acc[4][4] = {};
    f32x4 pA0, pA1;

    // ---- prologue ----
    if (tid < 256) {               // issue A(0)
        pA0 = *reinterpret_cast<const f32x4*>(aeb);
        pA1 = *reinterpret_cast<const f32x4*>(aeb + 4);
    }
#pragma unroll
    for (int i = 0; i < 4; ++i)    // gll B(0) -> Bsm buf0 (wave-private frags)
        __builtin_amdgcn_global_load_lds(
            (as1_uint*)(gsrc + (size_t)i * 512),
            (as3_uint*)((char*)Bsm + wn * 4096 + i * 1024), 16, 0, 0);
    if (tid < 256) {               // cvt+write A(0) (compiler waits its vmcnt)
        union { unsigned short h[8]; uint4 u; } u;
#pragma unroll
        for (int j = 0; j < 4; ++j) { u.h[j] = f2bf(pA0[j]); u.h[4 + j] = f2bf(pA1[j]); }
        *reinterpret_cast<uint4*>((char*)Asm + awb) = u.u;
    }
    asm volatile("s_waitcnt lgkmcnt(0)" ::: "memory");
    __builtin_amdgcn_sched_barrier(0);
    __builtin_amdgcn_s_barrier();
    __builtin_amdgcn_sched_barrier(0);

#pragma unroll 2
    for (int t = 0; t < NKT3; ++t) {
        const int cur = t & 1, nxt = cur ^ 1;
        // B(t) gll (issued at t-1) is one tile old -> near-free drain
        asm volatile("s_waitcnt vmcnt(0)" ::: "memory");
        __builtin_amdgcn_sched_barrier(0);
        // issue A(t+1) fp32 (HBM, full tile of flight)
        if (t + 1 < NKT3 && tid < 256) {
            const float* src = (t + 1 < 16) ? (aeb + (t + 1) * 32)
                                            : (acb + (t - 15) * 32);
            pA0 = *reinterpret_cast<const f32x4*>(src);
            pA1 = *reinterpret_cast<const f32x4*>(src + 4);
        }
        // ds_read fragments for tile t
        bf16x8 af[4], bf[4];
#pragma unroll
        for (int mi = 0; mi < 4; ++mi)
            af[mi] = *reinterpret_cast<const bf16x8*>(
                (char*)Asm + cur * 4096 + mi * 1024 + arb);
#pragma unroll
        for (int ni = 0; ni < 4; ++ni)
            bf[ni] = *reinterpret_cast<const bf16x8*>(
                (char*)Bsm + cur * 32768 + ni * 1024 + brb);
        // issue gll B(t+1) into other buffer (wave-private, no hazard)
        if (t + 1 < NKT3) {
            const unsigned short* gs = gsrc + (size_t)(t + 1) * 32 * 64 * 8;
#pragma unroll
            for (int i = 0; i < 4; ++i)
                __builtin_amdgcn_global_load_lds(
                    (as1_uint*)(gs + (size_t)i * 512),
                    (as3_uint*)((char*)Bsm + nxt * 32768 + wn * 4096 + i * 1024),
                    16, 0, 0);
        }
        __builtin_amdgcn_sched_barrier(0);
        // MFMA cluster (compiler inserts counted lgkm waits)
        __builtin_amdgcn_s_setprio(1);
#pragma unroll
        for (int mi = 0; mi < 4; ++mi)
#pragma unroll
            for (int ni = 0; ni < 4; ++ni)
                acc[mi][ni] = __builtin_amdgcn_mfma_f32_16x16x32_bf16(
                    af[mi], bf[ni], acc[mi][ni], 0, 0, 0);
        __builtin_amdgcn_s_setprio(0);
        // cvt + stage A(t+1) (counted vmcnt wait on pA only)
        if (t + 1 < NKT3 && tid < 256) {
            union { unsigned short h[8]; uint4 u; } u;
#pragma unroll
            for (int j = 0; j < 4; ++j) { u.h[j] = f2bf(pA0[j]); u.h[4 + j] = f2bf(pA1[j]); }
            *reinterpret_cast<uint4*>((char*)Asm + nxt * 4096 + awb) = u.u;
        }
        asm volatile("s_waitcnt lgkmcnt(0)" ::: "memory");
        __builtin_amdgcn_sched_barrier(0);
        __builtin_amdgcn_s_barrier();
        __builtin_amdgcn_sched_barrier(0);
    }

    // ---- epilogue: reuse Bsm space for qv/vv/sred ----
    float* qv   = (float*)lds;             // 512 f
    float* vv   = qv + 512;                // 512 f
    float* sred = vv + 512;                // 64 rows x 8 waves
    qv[tid] = q[(row0 >> 12) * H2 + tid];
    vv[tid] = vvec[tid];
    __syncthreads();

    float ps[4][4] = {};
#pragma unroll
    for (int mi = 0; mi < 4; ++mi)
#pragma unroll
        for (int ni = 0; ni < 4; ++ni) {
            int colg = wn * 64 + ni * 16 + (lane & 15);
            float qq = qv[colg], vl = vv[colg];
#pragma unroll
            for (int j = 0; j < 4; ++j) {
                float e = fast_tanh(acc[mi][ni][j] + qq);
                ps[mi][j] = fmaf(e, vl, ps[mi][j]);
            }
        }
#pragma unroll
    for (int mi = 0; mi < 4; ++mi)
#pragma unroll
        for (int j = 0; j < 4; ++j) {
            float s = ps[mi][j];
            s += __shfl_xor(s, 1);
            s += __shfl_xor(s, 2);
            s += __shfl_xor(s, 4);
            s += __shfl_xor(s, 8);
            if ((lane & 15) == 0)
                sred[(mi * 16 + (lane >> 4) * 4 + j) * 8 + wn] = s;
        }
    __syncthreads();
    if (tid < BM) {
        float s = 0.f;
#pragma unroll
        for (int w = 0; w < 8; ++w) s += sred[tid * 8 + w];
        scores[row0 + tid] = s;
    }
}

// ---------------------------------------------------------------------------
// Softmax over S per batch; also zeroes h_star (atomic target for kcov).
// ---------------------------------------------------------------------------
__global__ void ksoftmax(const float* __restrict__ scores, float* __restrict__ out) {
    __shared__ float redm[16];
    __shared__ float reds[16];
    int b = blockIdx.x, t = threadIdx.x, lane = t & 63, w = t >> 6;  // 1024 thr
    if (t < 512) out[b * 512 + t] = 0.0f;                            // zero h_star
    f32x4 sv = *reinterpret_cast<const f32x4*>(scores + b * 4096 + t * 4);
    float m = fmaxf(fmaxf(sv[0], sv[1]), fmaxf(sv[2], sv[3]));
#pragma unroll
    for (int o = 1; o < 64; o <<= 1) m = fmaxf(m, __shfl_xor(m, o));
    if (lane == 0) redm[w] = m;
    __syncthreads();
    float mm = redm[0];
#pragma unroll
    for (int i = 1; i < 16; ++i) mm = fmaxf(mm, redm[i]);

    f32x4 p;
#pragma unroll
    for (int j = 0; j < 4; ++j)
        p[j] = __builtin_amdgcn_exp2f((sv[j] - mm) * 1.4426950408889634f);
    float s = p[0] + p[1] + p[2] + p[3];
#pragma unroll
    for (int o = 1; o < 64; o <<= 1) s += __shfl_xor(s, o);
    if (lane == 0) reds[w] = s;
    __syncthreads();
    float tot = 0.f;
#pragma unroll
    for (int i = 0; i < 16; ++i) tot += reds[i];
    float rinv = __builtin_amdgcn_rcpf(tot);
    p *= rinv;
    *reinterpret_cast<f32x4*>(out + 16384 + b * 4096 + t * 4) = p;
}

// ---------------------------------------------------------------------------
// coverage_new = cov + attn (broadcast) ; h_star = sum_s attn * enc (atomic)
// ---------------------------------------------------------------------------
__global__ void kcov(const float* __restrict__ enc, const float* __restrict__ cov,
                     float* __restrict__ out) {
    const float* attn = out + 16384;
    float* covn  = out + 16384 + 131072;
    float* hstar = out;
    int blk = blockIdx.x;                    // 2048 = 32 b * 64 chunks
    int b = blk >> 6, ck = blk & 63;
    int s0 = ck * 64;
    int t  = threadIdx.x;                    // 256
    int f4 = (t & 127) * 4;
    int rp = t >> 7;
    size_t base = (size_t)b * SEQ * H2;
    f32x4 h = {0.f, 0.f, 0.f, 0.f};
#pragma unroll 2
    for (int i = 0; i < 32; ++i) {
        int s = s0 + i * 2 + rp;
        float a = attn[b * 4096 + s];
        size_t idx = base + (size_t)s * H2 + f4;
        f32x4 e4 = *reinterpret_cast<const f32x4*>(enc + idx);
        f32x4 c4 = *reinterpret_cast<const f32x4*>(cov + idx);
        c4 += a;
        __builtin_nontemporal_store(c4, reinterpret_cast<f32x4*>(covn + idx));
        h += a * e4;
    }
    int off = b * 512 + f4;
    atomicAdd(&hstar[off + 0], h[0]);
    atomicAdd(&hstar[off + 1], h[1]);
    atomicAdd(&hstar[off + 2], h[2]);
    atomicAdd(&hstar[off + 3], h[3]);
}

extern "C" void kernel_launch(void* const* d_in, const int* in_sizes, int n_in,
                              void* d_out, int out_size, void* d_ws, size_t ws_size,
                              hipStream_t stream) {
    const float* dec = (const float*)d_in[0];
    const float* enc = (const float*)d_in[1];
    const float* cov = (const float*)d_in[2];
    const float* Wh  = (const float*)d_in[3];
    const float* bh  = (const float*)d_in[4];
    const float* Ws  = (const float*)d_in[5];
    const float* bs  = (const float*)d_in[6];
    const float* Wc  = (const float*)d_in[7];
    const float* bc  = (const float*)d_in[8];
    const float* v   = (const float*)d_in[9];
    float* out = (float*)d_out;

    char* ws = (char*)d_ws;
    unsigned short* wt = (unsigned short*)ws;                 // 1 MB bf16 weights
    float* q      = (float*)(ws + (1 << 20));                 // 64 KB
    float* scores = (float*)(ws + (1 << 20) + 65536);         // 512 KB

    static bool attr_done = false;   // host-side, deterministic (same every call)
    if (!attr_done) {
        hipFuncSetAttribute((const void*)kgemm,
                            hipFuncAttributeMaxDynamicSharedMemorySize, 73728);
        attr_done = true;
    }

    kprep_w <<<dim3(256),  dim3(256),  0,     stream>>>(Wh, Wc, wt);
    kprep_q <<<dim3(32),   dim3(256),  0,     stream>>>(dec, Ws, bh, bs, bc, q);
    kgemm   <<<dim3(2048), dim3(512),  73728, stream>>>(enc, cov, wt, q, v, scores);
    ksoftmax<<<dim3(32),   dim3(1024), 0,     stream>>>(scores, out);
    kcov    <<<dim3(2048), dim3(256),  0,     stream>>>(enc, cov, out);
}

// Round 5
// 403.897 us; speedup vs baseline: 1.0270x; 1.0270x over previous
//
#include <hip/hip_runtime.h>
#include <hip/hip_bf16.h>
#include <stdint.h>

#define H2    512
#define BATCH 32
#define SEQ   4096
#define BM    64
#define NKT3  32          // 1024 / 32

typedef __attribute__((ext_vector_type(4))) float f32x4;
typedef __attribute__((ext_vector_type(8))) short bf16x8;

typedef __attribute__((address_space(3))) unsigned int       as3_uint;
typedef const __attribute__((address_space(1))) unsigned int as1_uint;

__device__ __forceinline__ unsigned short f2bf(float f) {
    union { float f; unsigned u; } v; v.f = f;
    unsigned r = v.u + 0x7FFF + ((v.u >> 16) & 1);
    return (unsigned short)(r >> 16);
}

__device__ __forceinline__ uint2 cvt4_bf16(f32x4 a) {
    uint2 r;
    asm("v_cvt_pk_bf16_f32 %0, %1, %2" : "=v"(r.x) : "v"(a[0]), "v"(a[1]));
    asm("v_cvt_pk_bf16_f32 %0, %1, %2" : "=v"(r.y) : "v"(a[2]), "v"(a[3]));
    return r;
}

__device__ __forceinline__ float fast_tanh(float x) {
    float e = __builtin_amdgcn_exp2f(x * 2.88539008177793f);
    return 1.0f - 2.0f * __builtin_amdgcn_rcpf(e + 1.0f);
}

// ---------------------------------------------------------------------------
// Prep 1: W = [W_h; W_c] -> bf16 FRAGMENT-MAJOR (unchanged layout):
// chunk c = (kt32*32 + cb)*64 + lane holds 16B:
//   B[col = cb*16 + (lane&15)][k = kt32*32 + (lane>>4)*8 + j], j=0..7
// ---------------------------------------------------------------------------
__global__ void kprep_w(const float* __restrict__ Wh, const float* __restrict__ Wc,
                        unsigned short* __restrict__ wt) {
    int c    = blockIdx.x * blockDim.x + threadIdx.x;   // 65536 chunks
    int lane = c & 63;
    int cb   = (c >> 6) & 31;
    int kt   = c >> 11;                                  // 0..31
    int col  = cb * 16 + (lane & 15);
    int k0   = kt * 32 + (lane >> 4) * 8;
    unsigned short tmp[8];
#pragma unroll
    for (int j = 0; j < 8; ++j) {
        int kg = k0 + j;
        float w = (kg < 512) ? Wh[kg * 512 + col] : Wc[(kg - 512) * 512 + col];
        tmp[j] = f2bf(w);
    }
    *reinterpret_cast<uint4*>(wt + (size_t)c * 8) = *reinterpret_cast<const uint4*>(tmp);
}

// ---------------------------------------------------------------------------
// Prep 2: q[b][h] = dec[b]@W_s + b_h + b_s + b_c
// ---------------------------------------------------------------------------
__global__ void kprep_q(const float* __restrict__ dec, const float* __restrict__ Ws,
                        const float* __restrict__ bh, const float* __restrict__ bs,
                        const float* __restrict__ bc, float* __restrict__ q) {
    __shared__ float dsh[512];
    int b = blockIdx.x, t = threadIdx.x;               // 256 threads
    dsh[t]       = dec[b * 512 + t];
    dsh[t + 256] = dec[b * 512 + 256 + t];
    __syncthreads();
    float a0 = 0.f, a1 = 0.f;
#pragma unroll 4
    for (int k = 0; k < 512; ++k) {
        float d = dsh[k];
        a0 = fmaf(d, Ws[k * 512 + t], a0);
        a1 = fmaf(d, Ws[k * 512 + 256 + t], a1);
    }
    q[b * 512 + t]       = a0 + bh[t] + bs[t] + bc[t];
    q[b * 512 + 256 + t] = a1 + bh[256 + t] + bs[256 + t] + bc[256 + t];
}

// ---------------------------------------------------------------------------
// Main fused GEMM v4. Pipeline with vmcnt issue-order control:
//   per tile t: [vmcnt(1)] [gll B(t+1)] [glb A(t+2)] [ds_read+MFMA]
//               [cvt+write A(t+1)] [lgkm(0); barrier]
//   entry vmcnt(1) drains B(t) (L2, 1 tile old = free) and KEEPS A(t+1)
//   in flight; A(t+1) drains at the cvt via compiler counted wait
//   (flight ~1.5 tiles > 900cy HBM latency).
// ---------------------------------------------------------------------------
__launch_bounds__(512, 4)
__global__ void kgemm(const float* __restrict__ enc, const float* __restrict__ cov,
                      const unsigned short* __restrict__ wt,
                      const float* __restrict__ q, const float* __restrict__ vvec,
                      float* __restrict__ scores) {
    extern __shared__ char lds[];
    unsigned short* Bsm = (unsigned short*)lds;          // 2 x 32KB
    unsigned short* Asm = (unsigned short*)(lds + 65536); // 2 x 4KB

    int tid  = threadIdx.x;
    int lane = tid & 63, wn = tid >> 6;

    int cpx  = gridDim.x >> 3;
    int swz  = (blockIdx.x & 7) * cpx + (blockIdx.x >> 3);
    int row0 = swz * BM;

    // ---- A staging (all 512 threads, 16B each): r = tid>>3, k4 = tid&7 ----
    int r = tid >> 3, k4 = tid & 7;
    const float* aeb = enc + (size_t)(row0 + r) * H2 + k4 * 4;
    const float* acb = cov + (size_t)(row0 + r) * H2 + k4 * 4;
    // frag-major bf16 write (b64), octet-XOR matches read swizzle:
    unsigned awb = (unsigned)((r >> 4) * 1024 + (k4 >> 1) * 256 +
                              (((r & 15) * 16) ^ ((k4 >> 1) << 4)) + (k4 & 1) * 8);
    // A frag read: byte = mi*1024 + (l>>4)*256 + ((l&15)*16 ^ ((l>>4)<<4))
    unsigned arb = (unsigned)((lane >> 4) * 256 +
                              (((lane & 15) * 16) ^ ((lane >> 4) << 4)));
    unsigned brb = (unsigned)(wn * 4096 + lane * 16);
    const unsigned short* gsrc = wt + ((size_t)wn * 4 * 64 + lane) * 8;

    f32x4 acc[4][4] = {};
    f32x4 pA[2];

#define ISSUE_B(T, BUF)                                                         \
    {                                                                           \
        const unsigned short* gs = gsrc + (size_t)(T) * 16384;                  \
        _Pragma("unroll")                                                       \
        for (int i = 0; i < 4; ++i)                                             \
            __builtin_amdgcn_global_load_lds(                                   \
                (as1_uint*)(gs + (size_t)i * 512),                              \
                (as3_uint*)((char*)Bsm + (BUF) * 32768 + wn * 4096 + i * 1024), \
                16, 0, 0);                                                      \
    }
#define A_SRC(T) (((T) < 16) ? (aeb + (T) * 32) : (acb + ((T) - 16) * 32))
#define DS_READS(BUF, AF, BF)                                                   \
    _Pragma("unroll")                                                           \
    for (int mi = 0; mi < 4; ++mi)                                              \
        AF[mi] = *reinterpret_cast<const bf16x8*>(                              \
            (char*)Asm + (BUF) * 4096 + mi * 1024 + arb);                       \
    _Pragma("unroll")                                                           \
    for (int ni = 0; ni < 4; ++ni)                                              \
        BF[ni] = *reinterpret_cast<const bf16x8*>(                              \
            (char*)Bsm + (BUF) * 32768 + ni * 1024 + brb);
#define MFMAS(AF, BF)                                                           \
    __builtin_amdgcn_s_setprio(1);                                              \
    _Pragma("unroll")                                                           \
    for (int mi = 0; mi < 4; ++mi)                                              \
        _Pragma("unroll")                                                       \
        for (int ni = 0; ni < 4; ++ni)                                          \
            acc[mi][ni] = __builtin_amdgcn_mfma_f32_16x16x32_bf16(              \
                AF[mi], BF[ni], acc[mi][ni], 0, 0, 0);                          \
    __builtin_amdgcn_s_setprio(0);
#define STAGE_A(PAR, BUF)                                                       \
    {                                                                           \
        uint2 u = cvt4_bf16(pA[PAR]);                                           \
        *reinterpret_cast<uint2*>((char*)Asm + (BUF) * 4096 + awb) = u;         \
    }
#define FENCE_BAR                                                               \
    asm volatile("s_waitcnt lgkmcnt(0)" ::: "memory");                          \
    __builtin_amdgcn_sched_barrier(0);                                          \
    __builtin_amdgcn_s_barrier();                                               \
    __builtin_amdgcn_sched_barrier(0);

    // ---- prologue: B(0) gll; A(0)->tmp; A(1)->pA[1]; stage A(0) ----
    ISSUE_B(0, 0)
    __builtin_amdgcn_sched_barrier(0);
    f32x4 a0 = *reinterpret_cast<const f32x4*>(A_SRC(0));
    pA[1]    = *reinterpret_cast<const f32x4*>(A_SRC(1));
    __builtin_amdgcn_sched_barrier(0);
    {
        uint2 u = cvt4_bf16(a0);          // compiler waits vmcnt(1): drains B(0),A(0)
        *reinterpret_cast<uint2*>((char*)Asm + awb) = u;
    }
    FENCE_BAR

    // ---- main loop t = 0..29 (branch-free) ----
#pragma unroll 2
    for (int t = 0; t < NKT3 - 2; ++t) {
        const int cur = t & 1, nxt = cur ^ 1;
        asm volatile("s_waitcnt vmcnt(1)" ::: "memory");   // drain B(t); keep A(t+1)
        __builtin_amdgcn_sched_barrier(0);
        ISSUE_B(t + 1, nxt)
        __builtin_amdgcn_sched_barrier(0);
        pA[cur] = *reinterpret_cast<const f32x4*>(A_SRC(t + 2));
        __builtin_amdgcn_sched_barrier(0);
        bf16x8 af[4], bf[4];
        DS_READS(cur, af, bf)
        MFMAS(af, bf)
        STAGE_A(nxt, nxt)                 // cvt A(t+1): counted vmcnt keeps B(t+1),A(t+2)
        FENCE_BAR
    }

    // ---- t = 30 (cur=0): B(31) gll, no A issue ----
    {
        asm volatile("s_waitcnt vmcnt(1)" ::: "memory");
        __builtin_amdgcn_sched_barrier(0);
        ISSUE_B(31, 1)
        __builtin_amdgcn_sched_barrier(0);
        bf16x8 af[4], bf[4];
        DS_READS(0, af, bf)
        MFMAS(af, bf)
        STAGE_A(1, 1)                     // A(31) from pA[1]
        FENCE_BAR
    }
    // ---- t = 31 (cur=1) ----
    {
        asm volatile("s_waitcnt vmcnt(0)" ::: "memory");
        __builtin_amdgcn_sched_barrier(0);
        bf16x8 af[4], bf[4];
        DS_READS(1, af, bf)
        MFMAS(af, bf)
    }

    // ---- epilogue: tanh(x + q) * v, reduce over 512 cols -> scores ----
    float* qv   = (float*)lds;
    float* vv   = qv + 512;
    float* sred = vv + 512;
    __builtin_amdgcn_s_barrier();
    qv[tid] = q[(row0 >> 12) * H2 + tid];
    vv[tid] = vvec[tid];
    __syncthreads();

    float ps[4][4] = {};
#pragma unroll
    for (int mi = 0; mi < 4; ++mi)
#pragma unroll
        for (int ni = 0; ni < 4; ++ni) {
            int colg = wn * 64 + ni * 16 + (lane & 15);
            float qq = qv[colg], vl = vv[colg];
#pragma unroll
            for (int j = 0; j < 4; ++j) {
                float e = fast_tanh(acc[mi][ni][j] + qq);
                ps[mi][j] = fmaf(e, vl, ps[mi][j]);
            }
        }
#pragma unroll
    for (int mi = 0; mi < 4; ++mi)
#pragma unroll
        for (int j = 0; j < 4; ++j) {
            float s = ps[mi][j];
            s += __shfl_xor(s, 1);
            s += __shfl_xor(s, 2);
            s += __shfl_xor(s, 4);
            s += __shfl_xor(s, 8);
            if ((lane & 15) == 0)
                sred[(mi * 16 + (lane >> 4) * 4 + j) * 8 + wn] = s;
        }
    __syncthreads();
    if (tid < BM) {
        float s = 0.f;
#pragma unroll
        for (int w = 0; w < 8; ++w) s += sred[tid * 8 + w];
        scores[row0 + tid] = s;
    }
#undef ISSUE_B
#undef A_SRC
#undef DS_READS
#undef MFMAS
#undef STAGE_A
#undef FENCE_BAR
}

// ---------------------------------------------------------------------------
// Softmax over S per batch; also zeroes h_star (atomic target for kcov).
// ---------------------------------------------------------------------------
__global__ void ksoftmax(const float* __restrict__ scores, float* __restrict__ out) {
    __shared__ float redm[16];
    __shared__ float reds[16];
    int b = blockIdx.x, t = threadIdx.x, lane = t & 63, w = t >> 6;  // 1024 thr
    if (t < 512) out[b * 512 + t] = 0.0f;                            // zero h_star
    f32x4 sv = *reinterpret_cast<const f32x4*>(scores + b * 4096 + t * 4);
    float m = fmaxf(fmaxf(sv[0], sv[1]), fmaxf(sv[2], sv[3]));
#pragma unroll
    for (int o = 1; o < 64; o <<= 1) m = fmaxf(m, __shfl_xor(m, o));
    if (lane == 0) redm[w] = m;
    __syncthreads();
    float mm = redm[0];
#pragma unroll
    for (int i = 1; i < 16; ++i) mm = fmaxf(mm, redm[i]);

    f32x4 p;
#pragma unroll
    for (int j = 0; j < 4; ++j)
        p[j] = __builtin_amdgcn_exp2f((sv[j] - mm) * 1.4426950408889634f);
    float s = p[0] + p[1] + p[2] + p[3];
#pragma unroll
    for (int o = 1; o < 64; o <<= 1) s += __shfl_xor(s, o);
    if (lane == 0) reds[w] = s;
    __syncthreads();
    float tot = 0.f;
#pragma unroll
    for (int i = 0; i < 16; ++i) tot += reds[i];
    float rinv = __builtin_amdgcn_rcpf(tot);
    p *= rinv;
    *reinterpret_cast<f32x4*>(out + 16384 + b * 4096 + t * 4) = p;
}

// ---------------------------------------------------------------------------
// coverage_new = cov + attn (broadcast) ; h_star = sum_s attn * enc (atomic)
// ---------------------------------------------------------------------------
__global__ void kcov(const float* __restrict__ enc, const float* __restrict__ cov,
                     float* __restrict__ out) {
    const float* attn = out + 16384;
    float* covn  = out + 16384 + 131072;
    float* hstar = out;
    int blk = blockIdx.x;                    // 2048 = 32 b * 64 chunks
    int b = blk >> 6, ck = blk & 63;
    int s0 = ck * 64;
    int t  = threadIdx.x;                    // 256
    int f4 = (t & 127) * 4;
    int rp = t >> 7;
    size_t base = (size_t)b * SEQ * H2;
    f32x4 h = {0.f, 0.f, 0.f, 0.f};
#pragma unroll 2
    for (int i = 0; i < 32; ++i) {
        int s = s0 + i * 2 + rp;
        float a = attn[b * 4096 + s];
        size_t idx = base + (size_t)s * H2 + f4;
        f32x4 e4 = *reinterpret_cast<const f32x4*>(enc + idx);
        f32x4 c4 = *reinterpret_cast<const f32x4*>(cov + idx);
        c4 += a;
        __builtin_nontemporal_store(c4, reinterpret_cast<f32x4*>(covn + idx));
        h += a * e4;
    }
    int off = b * 512 + f4;
    atomicAdd(&hstar[off + 0], h[0]);
    atomicAdd(&hstar[off + 1], h[1]);
    atomicAdd(&hstar[off + 2], h[2]);
    atomicAdd(&hstar[off + 3], h[3]);
}

extern "C" void kernel_launch(void* const* d_in, const int* in_sizes, int n_in,
                              void* d_out, int out_size, void* d_ws, size_t ws_size,
                              hipStream_t stream) {
    const float* dec = (const float*)d_in[0];
    const float* enc = (const float*)d_in[1];
    const float* cov = (const float*)d_in[2];
    const float* Wh  = (const float*)d_in[3];
    const float* bh  = (const float*)d_in[4];
    const float* Ws  = (const float*)d_in[5];
    const float* bs  = (const float*)d_in[6];
    const float* Wc  = (const float*)d_in[7];
    const float* bc  = (const float*)d_in[8];
    const float* v   = (const float*)d_in[9];
    float* out = (float*)d_out;

    char* ws = (char*)d_ws;
    unsigned short* wt = (unsigned short*)ws;                 // 1 MB bf16 weights
    float* q      = (float*)(ws + (1 << 20));                 // 64 KB
    float* scores = (float*)(ws + (1 << 20) + 65536);         // 512 KB

    static bool attr_done = false;
    if (!attr_done) {
        hipFuncSetAttribute((const void*)kgemm,
                            hipFuncAttributeMaxDynamicSharedMemorySize, 73728);
        attr_done = true;
    }

    kprep_w <<<dim3(256),  dim3(256),  0,     stream>>>(Wh, Wc, wt);
    kprep_q <<<dim3(32),   dim3(256),  0,     stream>>>(dec, Ws, bh, bs, bc, q);
    kgemm   <<<dim3(2048), dim3(512),  73728, stream>>>(enc, cov, wt, q, v, scores);
    ksoftmax<<<dim3(32),   dim3(1024), 0,     stream>>>(scores, out);
    kcov    <<<dim3(2048), dim3(256),  0,     stream>>>(enc, cov, out);
}

// Round 6
// 395.747 us; speedup vs baseline: 1.0482x; 1.0206x over previous
//
#include <hip/hip_runtime.h>
#include <hip/hip_bf16.h>
#include <stdint.h>

#define H2    512
#define BATCH 32
#define SEQ   4096
#define BM    64
#define NKT3  32          // 1024 / 32

typedef __attribute__((ext_vector_type(4))) float f32x4;
typedef __attribute__((ext_vector_type(8))) short bf16x8;

__device__ __forceinline__ unsigned short f2bf(float f) {
    union { float f; unsigned u; } v; v.f = f;
    unsigned r = v.u + 0x7FFF + ((v.u >> 16) & 1);
    return (unsigned short)(r >> 16);
}

__device__ __forceinline__ uint2 cvt4_bf16(f32x4 a) {
    uint2 r;
    asm("v_cvt_pk_bf16_f32 %0, %1, %2" : "=v"(r.x) : "v"(a[0]), "v"(a[1]));
    asm("v_cvt_pk_bf16_f32 %0, %1, %2" : "=v"(r.y) : "v"(a[2]), "v"(a[3]));
    return r;
}

__device__ __forceinline__ float fast_tanh(float x) {
    float e = __builtin_amdgcn_exp2f(x * 2.88539008177793f);
    return 1.0f - 2.0f * __builtin_amdgcn_rcpf(e + 1.0f);
}

// ---------------------------------------------------------------------------
// Prep 1: W = [W_h; W_c] -> bf16 FRAGMENT-MAJOR (unchanged layout):
// chunk c = (kt32*32 + cb)*64 + lane holds 16B:
//   B[col = cb*16 + (lane&15)][k = kt32*32 + (lane>>4)*8 + j], j=0..7
// ---------------------------------------------------------------------------
__global__ void kprep_w(const float* __restrict__ Wh, const float* __restrict__ Wc,
                        unsigned short* __restrict__ wt) {
    int c    = blockIdx.x * blockDim.x + threadIdx.x;   // 65536 chunks
    int lane = c & 63;
    int cb   = (c >> 6) & 31;
    int kt   = c >> 11;                                  // 0..31
    int col  = cb * 16 + (lane & 15);
    int k0   = kt * 32 + (lane >> 4) * 8;
    unsigned short tmp[8];
#pragma unroll
    for (int j = 0; j < 8; ++j) {
        int kg = k0 + j;
        float w = (kg < 512) ? Wh[kg * 512 + col] : Wc[(kg - 512) * 512 + col];
        tmp[j] = f2bf(w);
    }
    *reinterpret_cast<uint4*>(wt + (size_t)c * 8) = *reinterpret_cast<const uint4*>(tmp);
}

// ---------------------------------------------------------------------------
// Prep 2: q[b][h] = dec[b]@W_s + b_h + b_s + b_c
// ---------------------------------------------------------------------------
__global__ void kprep_q(const float* __restrict__ dec, const float* __restrict__ Ws,
                        const float* __restrict__ bh, const float* __restrict__ bs,
                        const float* __restrict__ bc, float* __restrict__ q) {
    __shared__ float dsh[512];
    int b = blockIdx.x, t = threadIdx.x;               // 256 threads
    dsh[t]       = dec[b * 512 + t];
    dsh[t + 256] = dec[b * 512 + 256 + t];
    __syncthreads();
    float a0 = 0.f, a1 = 0.f;
#pragma unroll 4
    for (int k = 0; k < 512; ++k) {
        float d = dsh[k];
        a0 = fmaf(d, Ws[k * 512 + t], a0);
        a1 = fmaf(d, Ws[k * 512 + 256 + t], a1);
    }
    q[b * 512 + t]       = a0 + bh[t] + bs[t] + bc[t];
    q[b * 512 + 256 + t] = a1 + bh[256 + t] + bs[256 + t] + bc[256 + t];
}

// ---------------------------------------------------------------------------
// Main fused GEMM v5: B never touches LDS.
//   B(t): 4 frags/wave straight from L2 to regs (single-buffered; issued
//         right after the MFMAs that consumed B(t-1); flight ~= stage+barrier
//         +ds_reads ~= L2 latency, remainder hidden by 2-blocks/CU TLP).
//   A: fp32 global (2 tiles ahead, HBM latency covered) -> cvt_pk bf16 ->
//      double-buffered 4KB LDS tiles.
//   LDS per window: ~72KB (was ~208KB) -> under MFMA time. <=128 VGPR ->
//   4 waves/SIMD.
// ---------------------------------------------------------------------------
__launch_bounds__(512, 4)
__global__ void kgemm(const float* __restrict__ enc, const float* __restrict__ cov,
                      const unsigned short* __restrict__ wt,
                      const float* __restrict__ q, const float* __restrict__ vvec,
                      float* __restrict__ scores) {
    __shared__ unsigned short Asm[2][2048];   // 2 x 4KB A tiles, frag-major
    __shared__ float qv[H2];
    __shared__ float vv[H2];
    __shared__ float sred[BM][8];

    int tid  = threadIdx.x;
    int lane = tid & 63, wn = tid >> 6;

    int cpx  = gridDim.x >> 3;
    int swz  = (blockIdx.x & 7) * cpx + (blockIdx.x >> 3);
    int row0 = swz * BM;

    // ---- A staging (512 threads x 16B): r = tid>>3, k4 = tid&7 ----
    int r = tid >> 3, k4 = tid & 7;
    const float* aeb = enc + (size_t)(row0 + r) * H2 + k4 * 4;
    const float* acb = cov + (size_t)(row0 + r) * H2 + k4 * 4;
    unsigned awb = (unsigned)((r >> 4) * 1024 + (k4 >> 1) * 256 +
                              (((r & 15) * 16) ^ ((k4 >> 1) << 4)) + (k4 & 1) * 8);
    unsigned arb = (unsigned)((lane >> 4) * 256 +
                              (((lane & 15) * 16) ^ ((lane >> 4) << 4)));
    // B frag base (fragment-major wt): frag(t,ni) at shorts offset
    //   ((t*32 + wn*4 + ni)*64 + lane)*8
    const unsigned short* bbase = wt + ((size_t)(wn * 4) * 64 + lane) * 8;

    f32x4  acc[4][4] = {};
    bf16x8 bfr[4];
    f32x4  pA[2];

#define A_SRC(T) (((T) < 16) ? (aeb + (T) * 32) : (acb + ((T) - 16) * 32))

    // ---- prologue: B(0)->regs; A(0)->stage; A(1)->pA[1] ----
#pragma unroll
    for (int ni = 0; ni < 4; ++ni)
        bfr[ni] = *reinterpret_cast<const bf16x8*>(bbase + ni * 512);
    f32x4 a0 = *reinterpret_cast<const f32x4*>(A_SRC(0));
    pA[1]    = *reinterpret_cast<const f32x4*>(A_SRC(1));
    __builtin_amdgcn_sched_barrier(0);
    {
        uint2 u = cvt4_bf16(a0);
        *reinterpret_cast<uint2*>((char*)Asm[0] + awb) = u;
    }
    asm volatile("s_waitcnt lgkmcnt(0)" ::: "memory");
    __builtin_amdgcn_sched_barrier(0);
    __builtin_amdgcn_s_barrier();
    __builtin_amdgcn_sched_barrier(0);

    // ---- main loop t = 0..29 ----
#pragma unroll 2
    for (int t = 0; t < NKT3 - 2; ++t) {
        const int cur = t & 1, nxt = cur ^ 1;
        // A-frag ds_reads for tile t
        bf16x8 af[4];
#pragma unroll
        for (int mi = 0; mi < 4; ++mi)
            af[mi] = *reinterpret_cast<const bf16x8*>(
                (char*)Asm[cur] + mi * 1024 + arb);
        // MFMA cluster consuming bfr(t) (auto counted vmcnt keeps A(t+1))
        __builtin_amdgcn_s_setprio(1);
#pragma unroll
        for (int mi = 0; mi < 4; ++mi)
#pragma unroll
            for (int ni = 0; ni < 4; ++ni)
                acc[mi][ni] = __builtin_amdgcn_mfma_f32_16x16x32_bf16(
                    af[mi], bfr[ni], acc[mi][ni], 0, 0, 0);
        __builtin_amdgcn_s_setprio(0);
        __builtin_amdgcn_sched_barrier(0);
        // issue B(t+1) -> regs (consumed next tile after barrier+ds_reads)
#pragma unroll
        for (int ni = 0; ni < 4; ++ni)
            bfr[ni] = *reinterpret_cast<const bf16x8*>(
                bbase + (size_t)(t + 1) * 16384 + ni * 512);
        // issue A(t+2) (HBM, ~1.3 tiles of flight)
        pA[cur] = *reinterpret_cast<const f32x4*>(A_SRC(t + 2));
        __builtin_amdgcn_sched_barrier(0);
        // cvt + stage A(t+1) into other buffer (counted vmcnt drains A(t+1))
        {
            uint2 u = cvt4_bf16(pA[nxt]);
            *reinterpret_cast<uint2*>((char*)Asm[nxt] + awb) = u;
        }
        asm volatile("s_waitcnt lgkmcnt(0)" ::: "memory");
        __builtin_amdgcn_sched_barrier(0);
        __builtin_amdgcn_s_barrier();
        __builtin_amdgcn_sched_barrier(0);
    }

    // ---- t = 30: B(31) issue, stage A(31), no new A ----
    {
        bf16x8 af[4];
#pragma unroll
        for (int mi = 0; mi < 4; ++mi)
            af[mi] = *reinterpret_cast<const bf16x8*>(
                (char*)Asm[0] + mi * 1024 + arb);
        __builtin_amdgcn_s_setprio(1);
#pragma unroll
        for (int mi = 0; mi < 4; ++mi)
#pragma unroll
            for (int ni = 0; ni < 4; ++ni)
                acc[mi][ni] = __builtin_amdgcn_mfma_f32_16x16x32_bf16(
                    af[mi], bfr[ni], acc[mi][ni], 0, 0, 0);
        __builtin_amdgcn_s_setprio(0);
        __builtin_amdgcn_sched_barrier(0);
#pragma unroll
        for (int ni = 0; ni < 4; ++ni)
            bfr[ni] = *reinterpret_cast<const bf16x8*>(
                bbase + (size_t)31 * 16384 + ni * 512);
        __builtin_amdgcn_sched_barrier(0);
        {
            uint2 u = cvt4_bf16(pA[1]);
            *reinterpret_cast<uint2*>((char*)Asm[1] + awb) = u;
        }
        asm volatile("s_waitcnt lgkmcnt(0)" ::: "memory");
        __builtin_amdgcn_sched_barrier(0);
        __builtin_amdgcn_s_barrier();
        __builtin_amdgcn_sched_barrier(0);
    }
    // ---- t = 31 ----
    {
        bf16x8 af[4];
#pragma unroll
        for (int mi = 0; mi < 4; ++mi)
            af[mi] = *reinterpret_cast<const bf16x8*>(
                (char*)Asm[1] + mi * 1024 + arb);
        __builtin_amdgcn_s_setprio(1);
#pragma unroll
        for (int mi = 0; mi < 4; ++mi)
#pragma unroll
            for (int ni = 0; ni < 4; ++ni)
                acc[mi][ni] = __builtin_amdgcn_mfma_f32_16x16x32_bf16(
                    af[mi], bfr[ni], acc[mi][ni], 0, 0, 0);
        __builtin_amdgcn_s_setprio(0);
    }
#undef A_SRC

    // ---- epilogue: tanh(x + q) * v, reduce over 512 cols -> scores ----
    qv[tid] = q[(row0 >> 12) * H2 + tid];
    vv[tid] = vvec[tid];
    __syncthreads();

    float ps[4][4] = {};
#pragma unroll
    for (int mi = 0; mi < 4; ++mi)
#pragma unroll
        for (int ni = 0; ni < 4; ++ni) {
            int colg = wn * 64 + ni * 16 + (lane & 15);
            float qq = qv[colg], vl = vv[colg];
#pragma unroll
            for (int j = 0; j < 4; ++j) {
                float e = fast_tanh(acc[mi][ni][j] + qq);
                ps[mi][j] = fmaf(e, vl, ps[mi][j]);
            }
        }
#pragma unroll
    for (int mi = 0; mi < 4; ++mi)
#pragma unroll
        for (int j = 0; j < 4; ++j) {
            float s = ps[mi][j];
            s += __shfl_xor(s, 1);
            s += __shfl_xor(s, 2);
            s += __shfl_xor(s, 4);
            s += __shfl_xor(s, 8);
            if ((lane & 15) == 0)
                sred[mi * 16 + (lane >> 4) * 4 + j][wn] = s;
        }
    __syncthreads();
    if (tid < BM) {
        float s = 0.f;
#pragma unroll
        for (int w = 0; w < 8; ++w) s += sred[tid][w];
        scores[row0 + tid] = s;
    }
}

// ---------------------------------------------------------------------------
// Softmax over S per batch; also zeroes h_star (atomic target for kcov).
// ---------------------------------------------------------------------------
__global__ void ksoftmax(const float* __restrict__ scores, float* __restrict__ out) {
    __shared__ float redm[16];
    __shared__ float reds[16];
    int b = blockIdx.x, t = threadIdx.x, lane = t & 63, w = t >> 6;  // 1024 thr
    if (t < 512) out[b * 512 + t] = 0.0f;                            // zero h_star
    f32x4 sv = *reinterpret_cast<const f32x4*>(scores + b * 4096 + t * 4);
    float m = fmaxf(fmaxf(sv[0], sv[1]), fmaxf(sv[2], sv[3]));
#pragma unroll
    for (int o = 1; o < 64; o <<= 1) m = fmaxf(m, __shfl_xor(m, o));
    if (lane == 0) redm[w] = m;
    __syncthreads();
    float mm = redm[0];
#pragma unroll
    for (int i = 1; i < 16; ++i) mm = fmaxf(mm, redm[i]);

    f32x4 p;
#pragma unroll
    for (int j = 0; j < 4; ++j)
        p[j] = __builtin_amdgcn_exp2f((sv[j] - mm) * 1.4426950408889634f);
    float s = p[0] + p[1] + p[2] + p[3];
#pragma unroll
    for (int o = 1; o < 64; o <<= 1) s += __shfl_xor(s, o);
    if (lane == 0) reds[w] = s;
    __syncthreads();
    float tot = 0.f;
#pragma unroll
    for (int i = 0; i < 16; ++i) tot += reds[i];
    float rinv = __builtin_amdgcn_rcpf(tot);
    p *= rinv;
    *reinterpret_cast<f32x4*>(out + 16384 + b * 4096 + t * 4) = p;
}

// ---------------------------------------------------------------------------
// coverage_new = cov + attn (broadcast) ; h_star = sum_s attn * enc (atomic)
// ---------------------------------------------------------------------------
__global__ void kcov(const float* __restrict__ enc, const float* __restrict__ cov,
                     float* __restrict__ out) {
    const float* attn = out + 16384;
    float* covn  = out + 16384 + 131072;
    float* hstar = out;
    int blk = blockIdx.x;                    // 2048 = 32 b * 64 chunks
    int b = blk >> 6, ck = blk & 63;
    int s0 = ck * 64;
    int t  = threadIdx.x;                    // 256
    int f4 = (t & 127) * 4;
    int rp = t >> 7;
    size_t base = (size_t)b * SEQ * H2;
    f32x4 h = {0.f, 0.f, 0.f, 0.f};
#pragma unroll 2
    for (int i = 0; i < 32; ++i) {
        int s = s0 + i * 2 + rp;
        float a = attn[b * 4096 + s];
        size_t idx = base + (size_t)s * H2 + f4;
        f32x4 e4 = *reinterpret_cast<const f32x4*>(enc + idx);
        f32x4 c4 = *reinterpret_cast<const f32x4*>(cov + idx);
        c4 += a;
        __builtin_nontemporal_store(c4, reinterpret_cast<f32x4*>(covn + idx));
        h += a * e4;
    }
    int off = b * 512 + f4;
    atomicAdd(&hstar[off + 0], h[0]);
    atomicAdd(&hstar[off + 1], h[1]);
    atomicAdd(&hstar[off + 2], h[2]);
    atomicAdd(&hstar[off + 3], h[3]);
}

extern "C" void kernel_launch(void* const* d_in, const int* in_sizes, int n_in,
                              void* d_out, int out_size, void* d_ws, size_t ws_size,
                              hipStream_t stream) {
    const float* dec = (const float*)d_in[0];
    const float* enc = (const float*)d_in[1];
    const float* cov = (const float*)d_in[2];
    const float* Wh  = (const float*)d_in[3];
    const float* bh  = (const float*)d_in[4];
    const float* Ws  = (const float*)d_in[5];
    const float* bs  = (const float*)d_in[6];
    const float* Wc  = (const float*)d_in[7];
    const float* bc  = (const float*)d_in[8];
    const float* v   = (const float*)d_in[9];
    float* out = (float*)d_out;

    char* ws = (char*)d_ws;
    unsigned short* wt = (unsigned short*)ws;                 // 1 MB bf16 weights
    float* q      = (float*)(ws + (1 << 20));                 // 64 KB
    float* scores = (float*)(ws + (1 << 20) + 65536);         // 512 KB

    kprep_w <<<dim3(256),  dim3(256),  0, stream>>>(Wh, Wc, wt);
    kprep_q <<<dim3(32),   dim3(256),  0, stream>>>(dec, Ws, bh, bs, bc, q);
    kgemm   <<<dim3(2048), dim3(512),  0, stream>>>(enc, cov, wt, q, v, scores);
    ksoftmax<<<dim3(32),   dim3(1024), 0, stream>>>(scores, out);
    kcov    <<<dim3(2048), dim3(256),  0, stream>>>(enc, cov, out);
}